// Round 7
// baseline (75.661 us; speedup 1.0000x reference)
//
#include <hip/hip_runtime.h>

// WideModel: 8 hashed multi-hot features + sparse linear combine.
// Strategy R6: one WAVE per row, maximize per-wave memory-level parallelism.
//  - 8 coalesced feature loads issued up front
//  - 8 SEPARATE wave-private 128-slot LDS tables (features no longer
//    serialize through one table)
//  - write-winner dedupe (plain volatile stores, no atomics): round 0 for
//    all 8 features batched (writes back-to-back, then reads back-to-back
//    -> LDS round-trips overlap), short straggler loops per feature
//  - all 8 W gathers issued back-to-back at the end (8 scattered-load
//    instructions in flight per wave), then one reduce + one store

constexpr int B = 16384;
constexpr int L = 50;
constexpr int SLOTS = 128;

struct KArgs {
    const int*   x[8];
    const float* w[8];
    const float* bias;
    float*       out;
};

__global__ __launch_bounds__(256) void wide_mlp_kernel(KArgs a) {
    __shared__ unsigned tbl[4][8][SLOTS];   // 4 waves x 8 feats x 128 = 16 KB

    const int wave = threadIdx.x >> 6;
    const int lane = threadIdx.x & 63;
    const int row  = (blockIdx.x << 2) | wave;

    // ---- phase 1: all 8 feature rows in flight (coalesced 200 B each) ----
    int v[8];
    #pragma unroll
    for (int f = 0; f < 8; ++f)
        v[f] = (lane < L) ? a.x[f][row * L + lane] : -1;

    // ---- clear this wave's 4 KB of tables: 16x ds_write_b128 ----
    {
        uint4* t4 = reinterpret_cast<uint4*>(&tbl[wave][0][0]);
        const uint4 ff = {0xFFFFFFFFu, 0xFFFFFFFFu, 0xFFFFFFFFu, 0xFFFFFFFFu};
        #pragma unroll
        for (int i = 0; i < 4; ++i) t4[lane + 64 * i] = ff;
    }
    asm volatile("s_waitcnt lgkmcnt(0)" ::: "memory");

    // ---- hash all 8 (compile-time magic-mul mod) ----
    unsigned bin[8], h[8], packed[8];
    bool pend[8], keep[8];
    #pragma unroll
    for (int f = 0; f < 8; ++f) {
        bin[f]    = (f < 6) ? ((unsigned)v[f] % 100000u)
                            : ((unsigned)v[f] % 1000000u);
        packed[f] = (bin[f] << 6) | (unsigned)lane;      // bin<2^20 -> fits
        h[f]      = (bin[f] * 2654435761u) >> 25;        // [0,128)
        pend[f]   = (v[f] >= 0);
        keep[f]   = false;
    }

    // volatile: forbid forwarding away the winner arbitration
    volatile unsigned (*t)[SLOTS] = tbl[wave];

    // ---- round 0: all 8 writes back-to-back, then all 8 reads ----
    #pragma unroll
    for (int f = 0; f < 8; ++f)
        if (pend[f]) t[f][h[f]] = packed[f];
    unsigned r0[8];
    #pragma unroll
    for (int f = 0; f < 8; ++f)
        r0[f] = pend[f] ? t[f][h[f]] : 0u;

    #pragma unroll
    for (int f = 0; f < 8; ++f) {
        if (pend[f]) {
            if ((r0[f] >> 6) == bin[f]) {       // our bin owns the slot
                keep[f] = (r0[f] == packed[f]); // exactly one winner lane
                pend[f] = false;
            } else {
                h[f] = (h[f] + 1) & (SLOTS - 1);
            }
        }
    }

    // ---- straggler rounds (rare; bin-groups travel in lockstep) ----
    #pragma unroll
    for (int f = 0; f < 8; ++f) {
        while (__any(pend[f])) {
            if (pend[f]) {
                t[f][h[f]] = packed[f];
                const unsigned r = t[f][h[f]];
                if ((r >> 6) == bin[f]) {
                    keep[f] = (r == packed[f]);
                    pend[f] = false;
                } else {
                    h[f] = (h[f] + 1) & (SLOTS - 1);
                }
            }
        }
    }

    // ---- phase 3: all 8 gathers issued back-to-back (max MLP) ----
    float wv[8];
    #pragma unroll
    for (int f = 0; f < 8; ++f)
        wv[f] = keep[f] ? a.w[f][bin[f]] : 0.0f;

    float acc = 0.0f;
    #pragma unroll
    for (int f = 0; f < 8; ++f) acc += wv[f];

    // ---- wave sum + single store ----
    #pragma unroll
    for (int off = 32; off; off >>= 1)
        acc += __shfl_xor(acc, off, 64);

    if (lane == 0) a.out[row] = acc + a.bias[0];
}

extern "C" void kernel_launch(void* const* d_in, const int* in_sizes, int n_in,
                              void* d_out, int out_size, void* d_ws, size_t ws_size,
                              hipStream_t stream) {
    KArgs a;
    for (int i = 0; i < 8; ++i) a.x[i] = (const int*)d_in[i];
    for (int i = 0; i < 8; ++i) a.w[i] = (const float*)d_in[8 + i];
    a.bias = (const float*)d_in[16];
    a.out  = (float*)d_out;

    wide_mlp_kernel<<<B / 4, 256, 0, stream>>>(a);
}

// Round 8
// 42.711 us; speedup vs baseline: 1.7714x; 1.7714x over previous
//
#include <hip/hip_runtime.h>
#include <hip/hip_fp16.h>

// WideModel: 8 hashed multi-hot features + sparse linear combine.
// Strategy R7 = R5 (wave/row, write-winner LDS dedupe) + FP16 weight tables.
// A pre-pass converts W fp32->fp16 into d_ws (5.2 MB); the scattered gathers
// then read 2B values from tables that nearly fit each XCD's 4MB L2,
// halving the dominant L2-fill traffic (bytes-bound hypothesis).

constexpr int B = 16384;
constexpr int L = 50;
constexpr int SLOTS = 128;

// padded fp16 table offsets in d_ws (elements; pads keep 4-elem alignment)
constexpr int FSZ = 100000, SSZ = 1000000;
constexpr int FPAD = 100096, SPAD = 1000064;        // %128 == 0
constexpr int OFF[8] = {0, FPAD, 2*FPAD, 3*FPAD, 4*FPAD, 5*FPAD,
                        6*FPAD, 6*FPAD + SPAD};
constexpr int TOTAL = 6*FPAD + 2*SPAD;              // 2,600,704 halves = 5.2 MB

struct KArgs {
    const int*    x[8];
    const __half* wt[8];   // fp16 tables in d_ws
    const float*  bias;
    float*        out;
};

struct CArgs {
    const float* src[8];
    __half*      dst;      // d_ws base
};

// ---- pre-pass: fp32 -> fp16 table conversion (each thread: 4 elements) ----
__global__ __launch_bounds__(256) void conv_kernel(CArgs c) {
    const int e = (blockIdx.x * 256 + (int)threadIdx.x) * 4;  // padded idx
    if (e >= TOTAL) return;

    int f = 7;
    #pragma unroll
    for (int i = 6; i >= 0; --i)
        if (e < OFF[i + 1]) f = i;

    const int idx = e - OFF[f];
    const int sz  = (f < 6) ? FSZ : SSZ;

    float4 v = {0.f, 0.f, 0.f, 0.f};
    if (idx < sz)   // pad chunks are whole (pads %4==0): no partial reads
        v = reinterpret_cast<const float4*>(c.src[f])[idx >> 2];

    __half2 lo = __floats2half2_rn(v.x, v.y);
    __half2 hi = __floats2half2_rn(v.z, v.w);
    *reinterpret_cast<__half2*>(c.dst + e)     = lo;
    *reinterpret_cast<__half2*>(c.dst + e + 2) = hi;
}

// ---- main: wave per row, write-winner dedupe (R5), fp16 gathers ----
__global__ __launch_bounds__(256) void wide_fp16_kernel(KArgs a) {
    __shared__ unsigned tbl[4][SLOTS];            // 2 KB/block, wave-private

    const int wave = threadIdx.x >> 6;
    const int lane = threadIdx.x & 63;
    const int row  = (blockIdx.x << 2) | wave;

    // prefetch all 8 feature rows (coalesced 200 B segments)
    int v[8];
    #pragma unroll
    for (int f = 0; f < 8; ++f)
        v[f] = (lane < L) ? a.x[f][row * L + lane] : -1;

    volatile unsigned* t = tbl[wave];

    float acc = 0.0f;

    #pragma unroll
    for (int f = 0; f < 8; ++f) {
        const bool valid = (v[f] >= 0);
        const unsigned bin = (f < 6) ? ((unsigned)v[f] % 100000u)
                                     : ((unsigned)v[f] % 1000000u);

        // clear table (packed < 2^26, so ~0 never matches a bin group)
        t[lane]      = 0xFFFFFFFFu;
        t[lane + 64] = 0xFFFFFFFFu;
        // same-wave LDS ops process in order; no barrier needed

        const unsigned packed = (bin << 6) | (unsigned)lane;
        unsigned h = (bin * 2654435761u) >> 25;   // top 7 bits -> [0,128)
        bool pend = valid, keep = false;

        while (__any(pend)) {
            if (pend) {
                t[h] = packed;                    // HW picks one winner
                const unsigned r = t[h];
                if ((r >> 6) == bin) {            // our bin owns the slot
                    keep = (r == packed);         // exactly one keeper/bin
                    pend = false;
                } else {
                    h = (h + 1) & (SLOTS - 1);    // foreign bin: probe on
                }
            }
        }

        if (keep) acc += __half2float(a.wt[f][bin]);
    }

    // wave sum + single store
    #pragma unroll
    for (int off = 32; off; off >>= 1)
        acc += __shfl_xor(acc, off, 64);

    if (lane == 0) a.out[row] = acc + a.bias[0];
}

extern "C" void kernel_launch(void* const* d_in, const int* in_sizes, int n_in,
                              void* d_out, int out_size, void* d_ws, size_t ws_size,
                              hipStream_t stream) {
    __half* wbase = (__half*)d_ws;

    CArgs c;
    for (int i = 0; i < 8; ++i) c.src[i] = (const float*)d_in[8 + i];
    c.dst = wbase;
    conv_kernel<<<(TOTAL / 4 + 255) / 256, 256, 0, stream>>>(c);

    KArgs a;
    for (int i = 0; i < 8; ++i) a.x[i]  = (const int*)d_in[i];
    for (int i = 0; i < 8; ++i) a.wt[i] = wbase + OFF[i];
    a.bias = (const float*)d_in[16];
    a.out  = (float*)d_out;
    wide_fp16_kernel<<<B / 4, 256, 0, stream>>>(a);
}